// Round 5
// baseline (784.419 us; speedup 1.0000x reference)
//
#include <hip/hip_runtime.h>
#include <hip/hip_bf16.h>

typedef __attribute__((ext_vector_type(4))) float f32x4;
typedef __attribute__((ext_vector_type(8))) short bfrag;   // 8 bf16 = 4 VGPRs
typedef __attribute__((ext_vector_type(4))) float facc;    // MFMA C/D
typedef __attribute__((ext_vector_type(8))) ushort u16x8;  // 16B of bf16

#define N_MOVES 200000
#define N_EDGES 1600000
#define DEMB 256
#define KD 512          // 2*D, also layer-2 K
#define H1D 512
#define H2D 256
#define MT 64           // moves per block
#define NTHREADS 512    // 8 waves; LDS ~67KB -> 2 blocks/CU -> 4 waves/SIMD

__device__ __forceinline__ ushort f2b(float f) {   // f32 -> bf16 RNE
  union { float f; unsigned u; } x; x.f = f;
  unsigned r = (x.u + 0x7fffu + ((x.u >> 16) & 1u)) >> 16;
  return (ushort)r;
}
__device__ __forceinline__ float b2f(ushort h) {
  union { unsigned u; float f; } x; x.u = ((unsigned)h) << 16;
  return x.f;
}

// ---- prep: W1 [512,512] f32 -> bf16 ; W2 [256,512] f32 -> bf16 (into ws) ----
__global__ void convert_w(const float* __restrict__ W1, const float* __restrict__ W2,
                          ushort* __restrict__ Wb) {
  int i = (blockIdx.x * 256 + threadIdx.x) * 4;
  const int n1 = H1D * KD;  // 262144
  if (i < n1) {
    f32x4 v = *(const f32x4*)(W1 + i);
    ushort4 h = { f2b(v.x), f2b(v.y), f2b(v.z), f2b(v.w) };
    *(ushort4*)(Wb + i) = h;
  } else {
    int j = i - n1;          // < 131072
    f32x4 v = *(const f32x4*)(W2 + j);
    ushort4 h = { f2b(v.x), f2b(v.y), f2b(v.z), f2b(v.w) };
    *(ushort4*)(Wb + n1 + j) = h;
  }
}

// ---- prep: embedding table f32 -> bf16 (25.6M elems) ----
__global__ void convert_emb(const float* __restrict__ E, ushort* __restrict__ Eb) {
  int i = (blockIdx.x * 256 + threadIdx.x) * 8;
  f32x4 a = *(const f32x4*)(E + i);
  f32x4 b = *(const f32x4*)(E + i + 4);
  u16x8 h = { f2b(a.x), f2b(a.y), f2b(a.z), f2b(a.w),
              f2b(b.x), f2b(b.y), f2b(b.z), f2b(b.w) };
  *(u16x8*)(Eb + i) = h;
}

// ---- fused gather + 3-layer MLP, in-place LDS (2 blocks/CU), reg-prefetched ----
template<int EMBBF>
__global__ __launch_bounds__(NTHREADS, 4)    // 4 waves/SIMD min -> VGPR cap 128
void fused_mlp(const float* __restrict__ emb,        // f32 table (fallback)
               const ushort* __restrict__ embb,      // bf16 table (fast path)
               const int* __restrict__ edge_index,   // [2][N_EDGES]
               const int* __restrict__ move_idx,     // [N_MOVES]
               const ushort* __restrict__ W1b,       // [512][512] bf16
               const float* __restrict__ b1,
               const ushort* __restrict__ W2b,       // [256][512] bf16
               const float* __restrict__ b2,
               const float* __restrict__ W3,         // [256] f32
               const float* __restrict__ b3,
               float* __restrict__ out)
{
  __shared__ ushort bufA[MT][KD];   // 64KB: X -> H1 (in place) -> H2 (first 32KB)
  __shared__ int   s_src[MT], s_tgt[MT];
  __shared__ float sW3[H2D];

  const int tid  = threadIdx.x;
  const int lane = tid & 63;
  const int wave = tid >> 6;        // 0..7
  const int m0   = blockIdx.x * MT;

  if (tid < MT) {
    int e = move_idx[m0 + tid];
    s_src[tid] = edge_index[e];
    s_tgt[tid] = edge_index[N_EDGES + e];
  }
  if (tid < H2D) sW3[tid] = W3[tid];
  __syncthreads();

  const int arow = lane & 15;            // M/N index within fragment
  const int akE  = (lane >> 4) << 3;     // k element base within 32-k step
  const int akB  = (lane >> 4) << 4;     // same, bytes

  // ---- W1 prologue prefetch (kk=0,1): in flight during gather ----
  const ushort* w1base = W1b + (size_t)(((wave << 6) + arow) * KD) + akE;  // wave owns 64 cols
  bfrag bcur[4], bnxt[4];
  #pragma unroll
  for (int ng = 0; ng < 4; ++ng) {
    bcur[ng] = *(const bfrag*)(w1base + (ng << 4) * KD);
    bnxt[ng] = *(const bfrag*)(w1base + (ng << 4) * KD + 32);
  }
  float bias1[4];
  #pragma unroll
  for (int ng = 0; ng < 4; ++ng) bias1[ng] = b1[(wave << 6) + (ng << 4) + arow];

  // ---- gather X[row] = concat(emb[src], emb[tgt]) bf16, swizzled; loads first ----
  if (EMBBF) {
    u16x8 gv[8];
    #pragma unroll
    for (int it = 0; it < 8; ++it) {                 // issue all 8 loads
      int u   = tid + it * NTHREADS;
      int row = u >> 6;
      int c8  = u & 63;
      const ushort* sp = (c8 < 32) ? (embb + (size_t)s_src[row] * DEMB + (c8 << 3))
                                   : (embb + (size_t)s_tgt[row] * DEMB + ((c8 - 32) << 3));
      gv[it] = *(const u16x8*)sp;
    }
    #pragma unroll
    for (int it = 0; it < 8; ++it) {                 // then all LDS writes
      int u   = tid + it * NTHREADS;
      int row = u >> 6;
      int c8  = u & 63;
      int bo  = (c8 << 4) ^ ((row & 7) << 4);
      *(u16x8*)((char*)(&bufA[row][0]) + bo) = gv[it];
    }
  } else {
    for (int u = tid; u < MT * 128; u += NTHREADS) {
      int row = u >> 7;
      int c4  = u & 127;
      const float* sp = (c4 < 64) ? (emb + (size_t)s_src[row] * DEMB + (c4 << 2))
                                  : (emb + (size_t)s_tgt[row] * DEMB + ((c4 - 64) << 2));
      f32x4 v = *(const f32x4*)sp;
      ushort4 h = { f2b(v.x), f2b(v.y), f2b(v.z), f2b(v.w) };
      int bo = (c4 << 3) ^ ((row & 7) << 4);
      *(ushort4*)((char*)(&bufA[row][0]) + bo) = h;
    }
  }
  __syncthreads();   // X ready

  // ================= layer 1: H1[64][512] = relu(X @ W1^T + b1) =================
  facc acc[4][4] = {};
  #pragma unroll
  for (int kk = 0; kk < 16; ++kk) {
    bfrag a[4];
    #pragma unroll
    for (int mg = 0; mg < 4; ++mg) {
      int row = (mg << 4) + arow;
      int bo = ((kk << 6) + akB) ^ ((row & 7) << 4);
      a[mg] = *(const bfrag*)((const char*)(&bufA[row][0]) + bo);
    }
    bfrag bn[4];
    if (kk < 14) {
      #pragma unroll
      for (int ng = 0; ng < 4; ++ng)
        bn[ng] = *(const bfrag*)(w1base + (ng << 4) * KD + ((kk + 2) << 5));
    }
    #pragma unroll
    for (int mg = 0; mg < 4; ++mg)
      #pragma unroll
      for (int ng = 0; ng < 4; ++ng)
        acc[mg][ng] = __builtin_amdgcn_mfma_f32_16x16x32_bf16(a[mg], bcur[ng], acc[mg][ng], 0, 0, 0);
    #pragma unroll
    for (int ng = 0; ng < 4; ++ng) { bcur[ng] = bnxt[ng]; bnxt[ng] = bn[ng]; }
  }

  // ---- W2 prologue prefetch (kk=0,1): lands across the next barriers ----
  const ushort* w2base = W2b + (size_t)(((wave << 5) + arow) * KD) + akE;  // wave owns 32 cols
  bfrag ccur[2], cnxt[2];
  ccur[0] = *(const bfrag*)(w2base);
  ccur[1] = *(const bfrag*)(w2base + (KD << 4));    // (16)*KD
  cnxt[0] = *(const bfrag*)(w2base + 32);
  cnxt[1] = *(const bfrag*)(w2base + (KD << 4) + 32);
  float bias2[2];
  #pragma unroll
  for (int ng = 0; ng < 2; ++ng) bias2[ng] = b2[(wave << 5) + (ng << 4) + arow];

  __syncthreads();   // all X reads done -> safe to overwrite bufA with H1

  // epilogue 1: +bias, relu, ->bf16 into bufA (H1, swizzled)
  #pragma unroll
  for (int ng = 0; ng < 4; ++ng) {
    int col = (wave << 6) + (ng << 4) + arow;
    #pragma unroll
    for (int mg = 0; mg < 4; ++mg) {
      #pragma unroll
      for (int r = 0; r < 4; ++r) {
        int row = (mg << 4) + ((lane >> 4) << 2) + r;    // C/D: row=(lane>>4)*4+r
        float v = fmaxf(acc[mg][ng][r] + bias1[ng], 0.f);
        int bo = (col << 1) ^ ((row & 7) << 4);
        *(ushort*)((char*)(&bufA[row][0]) + bo) = f2b(v);
      }
    }
  }
  __syncthreads();   // H1 ready

  // ================= layer 2: H2[64][256] = relu(H1 @ W2^T + b2) =================
  facc acc2[4][2] = {};
  #pragma unroll
  for (int kk = 0; kk < 16; ++kk) {
    bfrag a[4];
    #pragma unroll
    for (int mg = 0; mg < 4; ++mg) {
      int row = (mg << 4) + arow;
      int bo = ((kk << 6) + akB) ^ ((row & 7) << 4);
      a[mg] = *(const bfrag*)((const char*)(&bufA[row][0]) + bo);
    }
    bfrag cn[2];
    if (kk < 14) {
      cn[0] = *(const bfrag*)(w2base + ((kk + 2) << 5));
      cn[1] = *(const bfrag*)(w2base + (KD << 4) + ((kk + 2) << 5));
    }
    #pragma unroll
    for (int mg = 0; mg < 4; ++mg)
      #pragma unroll
      for (int ng = 0; ng < 2; ++ng)
        acc2[mg][ng] = __builtin_amdgcn_mfma_f32_16x16x32_bf16(a[mg], ccur[ng], acc2[mg][ng], 0, 0, 0);
    #pragma unroll
    for (int ng = 0; ng < 2; ++ng) { ccur[ng] = cnxt[ng]; cnxt[ng] = cn[ng]; }
  }
  __syncthreads();   // all H1 reads done -> safe to overwrite with H2

  // epilogue 2: H2 overlays first 32KB of bufA
  ushort (*H2s)[H2D] = (ushort(*)[H2D])bufA;
  #pragma unroll
  for (int ng = 0; ng < 2; ++ng) {
    int col = (wave << 5) + (ng << 4) + arow;
    #pragma unroll
    for (int mg = 0; mg < 4; ++mg) {
      #pragma unroll
      for (int r = 0; r < 4; ++r) {
        int row = (mg << 4) + ((lane >> 4) << 2) + r;
        float v = fmaxf(acc2[mg][ng][r] + bias2[ng], 0.f);
        int bo = (col << 1) ^ ((row & 7) << 4);
        *(ushort*)((char*)(&H2s[row][0]) + bo) = f2b(v);
      }
    }
  }
  __syncthreads();   // H2 ready

  // ================= layer 3: out[m] = H2[m] . W3 + b3 (8 lanes per move) =================
  {
    const float b3v = b3[0];
    int row = tid >> 3;          // 0..63
    int oct = tid & 7;           // 32 k's each
    float sum = 0.f;
    #pragma unroll
    for (int j = 0; j < 4; ++j) {
      int kb = (oct << 6) + (j << 4);                 // byte offset of k*2
      int bo = kb ^ ((row & 7) << 4);
      bfrag hv = *(const bfrag*)((const char*)(&H2s[row][0]) + bo);
      int k0 = (oct << 5) + (j << 3);
      #pragma unroll
      for (int e = 0; e < 8; ++e)
        sum += b2f((ushort)hv[e]) * sW3[k0 + e];
    }
    sum += __shfl_xor(sum, 1);
    sum += __shfl_xor(sum, 2);
    sum += __shfl_xor(sum, 4);
    if (oct == 0) out[m0 + row] = sum + b3v;
  }
}

extern "C" void kernel_launch(void* const* d_in, const int* in_sizes, int n_in,
                              void* d_out, int out_size, void* d_ws, size_t ws_size,
                              hipStream_t stream) {
  const float* emb        = (const float*)d_in[0];
  const int*   edge_index = (const int*)d_in[1];
  const int*   move_idx   = (const int*)d_in[2];
  const float* W1         = (const float*)d_in[3];
  const float* b1         = (const float*)d_in[4];
  const float* W2         = (const float*)d_in[5];
  const float* b2         = (const float*)d_in[6];
  const float* W3         = (const float*)d_in[7];
  const float* b3         = (const float*)d_in[8];
  float* out = (float*)d_out;

  ushort* Wb   = (ushort*)d_ws;                 // W1b [512*512] + W2b [256*512]
  ushort* Embb = Wb + (H1D * KD + H2D * KD);    // bf16 emb table [100000*256]
  const size_t need = (size_t)(H1D * KD + H2D * KD + 100000 * DEMB) * 2;

  convert_w<<<384, 256, 0, stream>>>(W1, W2, Wb);

  if (ws_size >= need) {
    convert_emb<<<12500, 256, 0, stream>>>(emb, Embb);
    fused_mlp<1><<<N_MOVES / MT, NTHREADS, 0, stream>>>(
        emb, Embb, edge_index, move_idx,
        Wb, b1, Wb + H1D * KD, b2, W3, b3, out);
  } else {
    fused_mlp<0><<<N_MOVES / MT, NTHREADS, 0, stream>>>(
        emb, Embb, edge_index, move_idx,
        Wb, b1, Wb + H1D * KD, b2, W3, b3, out);
  }
}

// Round 6
// 513.753 us; speedup vs baseline: 1.5268x; 1.5268x over previous
//
#include <hip/hip_runtime.h>
#include <hip/hip_bf16.h>

typedef __attribute__((ext_vector_type(4))) float f32x4;
typedef __attribute__((ext_vector_type(8))) short bfrag;   // 8 bf16 = 4 VGPRs
typedef __attribute__((ext_vector_type(4))) float facc;    // MFMA C/D
typedef __attribute__((ext_vector_type(8))) ushort u16x8;  // 16B of bf16

#define N_MOVES 200000
#define N_EDGES 1600000
#define DEMB 256
#define KD 512          // 2*D, also layer-2 K
#define H1D 512
#define H2D 256
#define MT 64           // moves per block
#define NTHREADS 512    // 8 waves; LDS ~67KB -> 2 blocks/CU -> 4 waves/SIMD

__device__ __forceinline__ ushort f2b(float f) {   // f32 -> bf16 RNE
  union { float f; unsigned u; } x; x.f = f;
  unsigned r = (x.u + 0x7fffu + ((x.u >> 16) & 1u)) >> 16;
  return (ushort)r;
}
__device__ __forceinline__ float b2f(ushort h) {
  union { unsigned u; float f; } x; x.u = ((unsigned)h) << 16;
  return x.f;
}

// ---- prep: W1 [512,512] f32 -> bf16 ; W2 [256,512] f32 -> bf16 (into ws) ----
__global__ void convert_w(const float* __restrict__ W1, const float* __restrict__ W2,
                          ushort* __restrict__ Wb) {
  int i = (blockIdx.x * 256 + threadIdx.x) * 4;
  const int n1 = H1D * KD;  // 262144
  if (i < n1) {
    f32x4 v = *(const f32x4*)(W1 + i);
    ushort4 h = { f2b(v.x), f2b(v.y), f2b(v.z), f2b(v.w) };
    *(ushort4*)(Wb + i) = h;
  } else {
    int j = i - n1;          // < 131072
    f32x4 v = *(const f32x4*)(W2 + j);
    ushort4 h = { f2b(v.x), f2b(v.y), f2b(v.z), f2b(v.w) };
    *(ushort4*)(Wb + n1 + j) = h;
  }
}

// ---- prep: embedding table f32 -> bf16 (25.6M elems) ----
__global__ void convert_emb(const float* __restrict__ E, ushort* __restrict__ Eb) {
  int i = (blockIdx.x * 256 + threadIdx.x) * 8;
  f32x4 a = *(const f32x4*)(E + i);
  f32x4 b = *(const f32x4*)(E + i + 4);
  u16x8 h = { f2b(a.x), f2b(a.y), f2b(a.z), f2b(a.w),
              f2b(b.x), f2b(b.y), f2b(b.z), f2b(b.w) };
  *(u16x8*)(Eb + i) = h;
}

// ---- fused gather + 3-layer MLP, in-place LDS (2 blocks/CU), DMA gather ----
template<int EMBBF>
__global__ __launch_bounds__(NTHREADS, 4)    // 4 waves/SIMD -> 128 unified regs/wave
void fused_mlp(const float* __restrict__ emb,        // f32 table (fallback)
               const ushort* __restrict__ embb,      // bf16 table (fast path)
               const int* __restrict__ edge_index,   // [2][N_EDGES]
               const int* __restrict__ move_idx,     // [N_MOVES]
               const ushort* __restrict__ W1b,       // [512][512] bf16
               const float* __restrict__ b1,
               const ushort* __restrict__ W2b,       // [256][512] bf16
               const float* __restrict__ b2,
               const float* __restrict__ W3,         // [256] f32
               const float* __restrict__ b3,
               float* __restrict__ out)
{
  __shared__ ushort bufA[MT][KD];   // 64KB: X -> H1 (in place) -> H2 (first 32KB)
  __shared__ int   s_src[MT], s_tgt[MT];
  __shared__ float sW3[H2D];

  const int tid  = threadIdx.x;
  const int lane = tid & 63;
  const int wave = tid >> 6;        // 0..7
  const int m0   = blockIdx.x * MT;

  if (tid < MT) {
    int e = move_idx[m0 + tid];
    s_src[tid] = edge_index[e];
    s_tgt[tid] = edge_index[N_EDGES + e];
  }
  if (tid < H2D) sW3[tid] = W3[tid];
  __syncthreads();

  const int arow = lane & 15;            // M/N index within fragment
  const int akE  = (lane >> 4) << 3;     // k element base within 32-k step
  const int akB  = (lane >> 4) << 4;     // same, bytes

  // ---- W1 prologue prefetch (kk=0,1): in flight during gather ----
  const ushort* w1base = W1b + (size_t)(((wave << 6) + arow) * KD) + akE;  // wave owns 64 cols
  bfrag bcur[4], bnxt[4];
  #pragma unroll
  for (int ng = 0; ng < 4; ++ng) {
    bcur[ng] = *(const bfrag*)(w1base + (ng << 4) * KD);
    bnxt[ng] = *(const bfrag*)(w1base + (ng << 4) * KD + 32);
  }
  float bias1[4];
  #pragma unroll
  for (int ng = 0; ng < 4; ++ng) bias1[ng] = b1[(wave << 6) + (ng << 4) + arow];

  // ---- gather: X[row] = concat(emb[src], emb[tgt]) bf16 ----
  if (EMBBF) {
    // DMA path: LDS linear, swizzle folded into per-lane GLOBAL granule index.
    // LDS granule l of row r must hold global granule l ^ (r&7)  (involution,
    // matches the ^((row&7)<<4) byte swizzle used by all LDS readers below).
    #pragma unroll
    for (int it = 0; it < 8; ++it) {
      int row  = (wave << 3) + it;
      int gl   = lane ^ (row & 7);        // stays within 8-granule window & half
      int node = (gl < 32) ? s_src[row] : s_tgt[row];
      const ushort* gp = embb + (size_t)node * DEMB + ((size_t)(gl & 31) << 3);
      __builtin_amdgcn_global_load_lds(
          (const __attribute__((address_space(1))) void*)gp,
          (__attribute__((address_space(3))) void*)(&bufA[row][0]),
          16, 0, 0);
    }
  } else {
    for (int u = tid; u < MT * 128; u += NTHREADS) {
      int row = u >> 7;
      int c4  = u & 127;
      const float* sp = (c4 < 64) ? (emb + (size_t)s_src[row] * DEMB + (c4 << 2))
                                  : (emb + (size_t)s_tgt[row] * DEMB + ((c4 - 64) << 2));
      f32x4 v = *(const f32x4*)sp;
      ushort4 h = { f2b(v.x), f2b(v.y), f2b(v.z), f2b(v.w) };
      int bo = (c4 << 3) ^ ((row & 7) << 4);
      *(ushort4*)((char*)(&bufA[row][0]) + bo) = h;
    }
  }
  __syncthreads();   // X ready (compiler drains vmcnt before s_barrier)

  // ================= layer 1: H1[64][512] = relu(X @ W1^T + b1) =================
  facc acc[4][4] = {};
  #pragma unroll
  for (int kk = 0; kk < 16; ++kk) {
    bfrag a[4];
    #pragma unroll
    for (int mg = 0; mg < 4; ++mg) {
      int row = (mg << 4) + arow;
      int bo = ((kk << 6) + akB) ^ ((row & 7) << 4);
      a[mg] = *(const bfrag*)((const char*)(&bufA[row][0]) + bo);
    }
    __builtin_amdgcn_s_setprio(1);
    #pragma unroll
    for (int mg = 0; mg < 4; ++mg)
      #pragma unroll
      for (int ng = 0; ng < 4; ++ng)
        acc[mg][ng] = __builtin_amdgcn_mfma_f32_16x16x32_bf16(a[mg], bcur[ng], acc[mg][ng], 0, 0, 0);
    __builtin_amdgcn_s_setprio(0);
    // rotate + issue kk+2 load (2 buffers, issue-at-end: ~1 iter of slack)
    #pragma unroll
    for (int ng = 0; ng < 4; ++ng) bcur[ng] = bnxt[ng];
    if (kk < 14) {
      #pragma unroll
      for (int ng = 0; ng < 4; ++ng)
        bnxt[ng] = *(const bfrag*)(w1base + (ng << 4) * KD + ((kk + 2) << 5));
    }
  }

  // ---- W2 prologue prefetch (kk=0,1): lands across the next barriers ----
  const ushort* w2base = W2b + (size_t)(((wave << 5) + arow) * KD) + akE;  // wave owns 32 cols
  bfrag ccur[2], cnxt[2];
  ccur[0] = *(const bfrag*)(w2base);
  ccur[1] = *(const bfrag*)(w2base + (KD << 4));    // +16*KD
  cnxt[0] = *(const bfrag*)(w2base + 32);
  cnxt[1] = *(const bfrag*)(w2base + (KD << 4) + 32);
  float bias2[2];
  #pragma unroll
  for (int ng = 0; ng < 2; ++ng) bias2[ng] = b2[(wave << 5) + (ng << 4) + arow];

  __syncthreads();   // all X reads done -> safe to overwrite bufA with H1

  // epilogue 1: +bias, relu, ->bf16 into bufA (H1, swizzled)
  #pragma unroll
  for (int ng = 0; ng < 4; ++ng) {
    int col = (wave << 6) + (ng << 4) + arow;
    #pragma unroll
    for (int mg = 0; mg < 4; ++mg) {
      #pragma unroll
      for (int r = 0; r < 4; ++r) {
        int row = (mg << 4) + ((lane >> 4) << 2) + r;    // C/D: row=(lane>>4)*4+r
        float v = fmaxf(acc[mg][ng][r] + bias1[ng], 0.f);
        int bo = (col << 1) ^ ((row & 7) << 4);
        *(ushort*)((char*)(&bufA[row][0]) + bo) = f2b(v);
      }
    }
  }
  __syncthreads();   // H1 ready

  // ================= layer 2: H2[64][256] = relu(H1 @ W2^T + b2) =================
  facc acc2[4][2] = {};
  #pragma unroll
  for (int kk = 0; kk < 16; ++kk) {
    bfrag a[4];
    #pragma unroll
    for (int mg = 0; mg < 4; ++mg) {
      int row = (mg << 4) + arow;
      int bo = ((kk << 6) + akB) ^ ((row & 7) << 4);
      a[mg] = *(const bfrag*)((const char*)(&bufA[row][0]) + bo);
    }
    __builtin_amdgcn_s_setprio(1);
    #pragma unroll
    for (int mg = 0; mg < 4; ++mg)
      #pragma unroll
      for (int ng = 0; ng < 2; ++ng)
        acc2[mg][ng] = __builtin_amdgcn_mfma_f32_16x16x32_bf16(a[mg], ccur[ng], acc2[mg][ng], 0, 0, 0);
    __builtin_amdgcn_s_setprio(0);
    #pragma unroll
    for (int ng = 0; ng < 2; ++ng) ccur[ng] = cnxt[ng];
    if (kk < 14) {
      cnxt[0] = *(const bfrag*)(w2base + ((kk + 2) << 5));
      cnxt[1] = *(const bfrag*)(w2base + (KD << 4) + ((kk + 2) << 5));
    }
  }
  __syncthreads();   // all H1 reads done -> safe to overwrite with H2

  // epilogue 2: H2 overlays first 32KB of bufA
  ushort (*H2s)[H2D] = (ushort(*)[H2D])bufA;
  #pragma unroll
  for (int ng = 0; ng < 2; ++ng) {
    int col = (wave << 5) + (ng << 4) + arow;
    #pragma unroll
    for (int mg = 0; mg < 4; ++mg) {
      #pragma unroll
      for (int r = 0; r < 4; ++r) {
        int row = (mg << 4) + ((lane >> 4) << 2) + r;
        float v = fmaxf(acc2[mg][ng][r] + bias2[ng], 0.f);
        int bo = (col << 1) ^ ((row & 7) << 4);
        *(ushort*)((char*)(&H2s[row][0]) + bo) = f2b(v);
      }
    }
  }
  __syncthreads();   // H2 ready

  // ================= layer 3: out[m] = H2[m] . W3 + b3 (8 lanes per move) =================
  {
    const float b3v = b3[0];
    int row = tid >> 3;          // 0..63
    int oct = tid & 7;           // 32 k's each
    float sum = 0.f;
    #pragma unroll
    for (int j = 0; j < 4; ++j) {
      int kb = (oct << 6) + (j << 4);                 // byte offset of k*2
      int bo = kb ^ ((row & 7) << 4);
      bfrag hv = *(const bfrag*)((const char*)(&H2s[row][0]) + bo);
      int k0 = (oct << 5) + (j << 3);
      #pragma unroll
      for (int e = 0; e < 8; ++e)
        sum += b2f((ushort)hv[e]) * sW3[k0 + e];
    }
    sum += __shfl_xor(sum, 1);
    sum += __shfl_xor(sum, 2);
    sum += __shfl_xor(sum, 4);
    if (oct == 0) out[m0 + row] = sum + b3v;
  }
}

extern "C" void kernel_launch(void* const* d_in, const int* in_sizes, int n_in,
                              void* d_out, int out_size, void* d_ws, size_t ws_size,
                              hipStream_t stream) {
  const float* emb        = (const float*)d_in[0];
  const int*   edge_index = (const int*)d_in[1];
  const int*   move_idx   = (const int*)d_in[2];
  const float* W1         = (const float*)d_in[3];
  const float* b1         = (const float*)d_in[4];
  const float* W2         = (const float*)d_in[5];
  const float* b2         = (const float*)d_in[6];
  const float* W3         = (const float*)d_in[7];
  const float* b3         = (const float*)d_in[8];
  float* out = (float*)d_out;

  ushort* Wb   = (ushort*)d_ws;                 // W1b [512*512] + W2b [256*512]
  ushort* Embb = Wb + (H1D * KD + H2D * KD);    // bf16 emb table [100000*256]
  const size_t need = (size_t)(H1D * KD + H2D * KD + 100000 * DEMB) * 2;

  convert_w<<<384, 256, 0, stream>>>(W1, W2, Wb);

  if (ws_size >= need) {
    convert_emb<<<12500, 256, 0, stream>>>(emb, Embb);
    fused_mlp<1><<<N_MOVES / MT, NTHREADS, 0, stream>>>(
        emb, Embb, edge_index, move_idx,
        Wb, b1, Wb + H1D * KD, b2, W3, b3, out);
  } else {
    fused_mlp<0><<<N_MOVES / MT, NTHREADS, 0, stream>>>(
        emb, Embb, edge_index, move_idx,
        Wb, b1, Wb + H1D * KD, b2, W3, b3, out);
  }
}

// Round 7
// 480.872 us; speedup vs baseline: 1.6312x; 1.0684x over previous
//
#include <hip/hip_runtime.h>
#include <hip/hip_bf16.h>

typedef __attribute__((ext_vector_type(4))) float f32x4;
typedef __attribute__((ext_vector_type(8))) short bfrag;   // 8 bf16 = 4 VGPRs
typedef __attribute__((ext_vector_type(4))) float facc;    // MFMA C/D
typedef __attribute__((ext_vector_type(8))) ushort u16x8;  // 16B of bf16

#define N_MOVES 200000
#define N_EDGES 1600000
#define DEMB 256
#define KD 512          // 2*D, also layer-2 K
#define H1D 512
#define H2D 256
#define MT 64           // moves per block
#define NTHREADS 512    // 8 waves; LDS ~67KB -> 2 blocks/CU -> 4 waves/SIMD

__device__ __forceinline__ ushort f2b(float f) {   // f32 -> bf16 RNE
  union { float f; unsigned u; } x; x.f = f;
  unsigned r = (x.u + 0x7fffu + ((x.u >> 16) & 1u)) >> 16;
  return (ushort)r;
}
__device__ __forceinline__ float b2f(ushort h) {
  union { unsigned u; float f; } x; x.u = ((unsigned)h) << 16;
  return x.f;
}

// ---- prep: W1 [512,512] f32 -> bf16 ; W2 [256,512] f32 -> bf16 (into ws) ----
__global__ void convert_w(const float* __restrict__ W1, const float* __restrict__ W2,
                          ushort* __restrict__ Wb) {
  int i = (blockIdx.x * 256 + threadIdx.x) * 4;
  const int n1 = H1D * KD;  // 262144
  if (i < n1) {
    f32x4 v = *(const f32x4*)(W1 + i);
    ushort4 h = { f2b(v.x), f2b(v.y), f2b(v.z), f2b(v.w) };
    *(ushort4*)(Wb + i) = h;
  } else {
    int j = i - n1;          // < 131072
    f32x4 v = *(const f32x4*)(W2 + j);
    ushort4 h = { f2b(v.x), f2b(v.y), f2b(v.z), f2b(v.w) };
    *(ushort4*)(Wb + n1 + j) = h;
  }
}

// ---- prep: embedding table f32 -> bf16 (25.6M elems) ----
__global__ void convert_emb(const float* __restrict__ E, ushort* __restrict__ Eb) {
  int i = (blockIdx.x * 256 + threadIdx.x) * 8;
  f32x4 a = *(const f32x4*)(E + i);
  f32x4 b = *(const f32x4*)(E + i + 4);
  u16x8 h = { f2b(a.x), f2b(a.y), f2b(a.z), f2b(a.w),
              f2b(b.x), f2b(b.y), f2b(b.z), f2b(b.w) };
  *(u16x8*)(Eb + i) = h;
}

// ---- fused gather + 3-layer MLP, in-place LDS, ping-pong B prefetch ----
template<int EMBBF>
__global__ __launch_bounds__(NTHREADS, 4)    // 4 waves/SIMD -> 128 unified regs/wave
void fused_mlp(const float* __restrict__ emb,        // f32 table (fallback)
               const ushort* __restrict__ embb,      // bf16 table (fast path)
               const int* __restrict__ edge_index,   // [2][N_EDGES]
               const int* __restrict__ move_idx,     // [N_MOVES]
               const ushort* __restrict__ W1b,       // [512][512] bf16
               const float* __restrict__ b1,
               const ushort* __restrict__ W2b,       // [256][512] bf16
               const float* __restrict__ b2,
               const float* __restrict__ W3,         // [256] f32
               const float* __restrict__ b3,
               float* __restrict__ out)
{
  __shared__ ushort bufA[MT][KD];   // 64KB: X -> H1 (in place) -> H2 (first 32KB)
  __shared__ int   s_src[MT], s_tgt[MT];
  __shared__ float sW3[H2D];

  const int tid  = threadIdx.x;
  const int lane = tid & 63;
  const int wave = tid >> 6;        // 0..7
  const int m0   = blockIdx.x * MT;

  if (tid < MT) {
    int e = move_idx[m0 + tid];
    s_src[tid] = edge_index[e];
    s_tgt[tid] = edge_index[N_EDGES + e];
  }
  if (tid < H2D) sW3[tid] = W3[tid];
  __syncthreads();

  const int arow = lane & 15;            // M/N index within fragment
  const int akE  = (lane >> 4) << 3;     // k element base within 32-k step
  const int akB  = (lane >> 4) << 4;     // same, bytes

  // W1 row pointers: wave owns 64 cols, 4 n-groups, kk offset folds into imm
  const ushort* wp0 = W1b + (size_t)(((wave << 6) + arow) * KD) + akE;
  const ushort* wp1 = wp0 + 16 * KD;
  const ushort* wp2 = wp0 + 32 * KD;
  const ushort* wp3 = wp0 + 48 * KD;

  // ---- W1 ping-pong prologue (kk=0 -> bA, kk=1 -> bB): in flight during gather ----
  bfrag bA[4], bB[4];
  bA[0] = *(const bfrag*)(wp0);      bA[1] = *(const bfrag*)(wp1);
  bA[2] = *(const bfrag*)(wp2);      bA[3] = *(const bfrag*)(wp3);
  bB[0] = *(const bfrag*)(wp0 + 32); bB[1] = *(const bfrag*)(wp1 + 32);
  bB[2] = *(const bfrag*)(wp2 + 32); bB[3] = *(const bfrag*)(wp3 + 32);

  // ---- gather: X[row] = concat(emb[src], emb[tgt]) bf16 ----
  if (EMBBF) {
    // DMA: LDS linear, swizzle folded into per-lane GLOBAL granule index.
    #pragma unroll
    for (int it = 0; it < 8; ++it) {
      int row  = (wave << 3) + it;
      int gl   = lane ^ (row & 7);        // involution, matches read swizzle
      int node = (gl < 32) ? s_src[row] : s_tgt[row];
      const ushort* gp = embb + (size_t)node * DEMB + ((size_t)(gl & 31) << 3);
      __builtin_amdgcn_global_load_lds(
          (const __attribute__((address_space(1))) void*)gp,
          (__attribute__((address_space(3))) void*)(&bufA[row][0]),
          16, 0, 0);
    }
  } else {
    for (int u = tid; u < MT * 128; u += NTHREADS) {
      int row = u >> 7;
      int c4  = u & 127;
      const float* sp = (c4 < 64) ? (emb + (size_t)s_src[row] * DEMB + (c4 << 2))
                                  : (emb + (size_t)s_tgt[row] * DEMB + ((c4 - 64) << 2));
      f32x4 v = *(const f32x4*)sp;
      ushort4 h = { f2b(v.x), f2b(v.y), f2b(v.z), f2b(v.w) };
      int bo = (c4 << 3) ^ ((row & 7) << 4);
      *(ushort4*)((char*)(&bufA[row][0]) + bo) = h;
    }
  }
  __syncthreads();   // X ready

  // ================= layer 1: H1[64][512] = relu(X @ W1^T + b1) =================
  facc acc[4][4] = {};
  #pragma unroll
  for (int kk2 = 0; kk2 < 8; ++kk2) {
    const int kk = kk2 << 1;
    // even step: consume bA
    __builtin_amdgcn_s_setprio(1);
    #pragma unroll
    for (int mg = 0; mg < 4; ++mg) {
      int row = (mg << 4) + arow;
      int bo = ((kk << 6) + akB) ^ ((row & 7) << 4);
      bfrag a = *(const bfrag*)((const char*)(&bufA[row][0]) + bo);
      #pragma unroll
      for (int ng = 0; ng < 4; ++ng)
        acc[mg][ng] = __builtin_amdgcn_mfma_f32_16x16x32_bf16(a, bA[ng], acc[mg][ng], 0, 0, 0);
    }
    __builtin_amdgcn_s_setprio(0);
    if (kk + 2 < 16) {   // refill bA for kk+2 (used next even step)
      bA[0] = *(const bfrag*)(wp0 + ((kk + 2) << 5));
      bA[1] = *(const bfrag*)(wp1 + ((kk + 2) << 5));
      bA[2] = *(const bfrag*)(wp2 + ((kk + 2) << 5));
      bA[3] = *(const bfrag*)(wp3 + ((kk + 2) << 5));
    }
    // odd step: consume bB
    __builtin_amdgcn_s_setprio(1);
    #pragma unroll
    for (int mg = 0; mg < 4; ++mg) {
      int row = (mg << 4) + arow;
      int bo = (((kk + 1) << 6) + akB) ^ ((row & 7) << 4);
      bfrag a = *(const bfrag*)((const char*)(&bufA[row][0]) + bo);
      #pragma unroll
      for (int ng = 0; ng < 4; ++ng)
        acc[mg][ng] = __builtin_amdgcn_mfma_f32_16x16x32_bf16(a, bB[ng], acc[mg][ng], 0, 0, 0);
    }
    __builtin_amdgcn_s_setprio(0);
    if (kk + 3 < 16) {   // refill bB for kk+3
      bB[0] = *(const bfrag*)(wp0 + ((kk + 3) << 5));
      bB[1] = *(const bfrag*)(wp1 + ((kk + 3) << 5));
      bB[2] = *(const bfrag*)(wp2 + ((kk + 3) << 5));
      bB[3] = *(const bfrag*)(wp3 + ((kk + 3) << 5));
    }
  }

  // ---- W2 ping-pong prologue: lands across the next barriers ----
  const ushort* cp0 = W2b + (size_t)(((wave << 5) + arow) * KD) + akE;  // 32 cols/wave
  const ushort* cp1 = cp0 + 16 * KD;
  bfrag cA[2], cB[2];
  cA[0] = *(const bfrag*)(cp0);      cA[1] = *(const bfrag*)(cp1);
  cB[0] = *(const bfrag*)(cp0 + 32); cB[1] = *(const bfrag*)(cp1 + 32);

  float bias1[4];
  #pragma unroll
  for (int ng = 0; ng < 4; ++ng) bias1[ng] = b1[(wave << 6) + (ng << 4) + arow];

  __syncthreads();   // all X reads done -> safe to overwrite bufA with H1

  // epilogue 1: +bias, relu, ->bf16 into bufA (H1, swizzled)
  #pragma unroll
  for (int ng = 0; ng < 4; ++ng) {
    int col = (wave << 6) + (ng << 4) + arow;
    #pragma unroll
    for (int mg = 0; mg < 4; ++mg) {
      #pragma unroll
      for (int r = 0; r < 4; ++r) {
        int row = (mg << 4) + ((lane >> 4) << 2) + r;    // C/D: row=(lane>>4)*4+r
        float v = fmaxf(acc[mg][ng][r] + bias1[ng], 0.f);
        int bo = (col << 1) ^ ((row & 7) << 4);
        *(ushort*)((char*)(&bufA[row][0]) + bo) = f2b(v);
      }
    }
  }
  __syncthreads();   // H1 ready

  // ================= layer 2: H2[64][256] = relu(H1 @ W2^T + b2) =================
  facc acc2[4][2] = {};
  #pragma unroll
  for (int kk2 = 0; kk2 < 8; ++kk2) {
    const int kk = kk2 << 1;
    __builtin_amdgcn_s_setprio(1);
    #pragma unroll
    for (int mg = 0; mg < 4; ++mg) {
      int row = (mg << 4) + arow;
      int bo = ((kk << 6) + akB) ^ ((row & 7) << 4);
      bfrag a = *(const bfrag*)((const char*)(&bufA[row][0]) + bo);
      #pragma unroll
      for (int ng = 0; ng < 2; ++ng)
        acc2[mg][ng] = __builtin_amdgcn_mfma_f32_16x16x32_bf16(a, cA[ng], acc2[mg][ng], 0, 0, 0);
    }
    __builtin_amdgcn_s_setprio(0);
    if (kk + 2 < 16) {
      cA[0] = *(const bfrag*)(cp0 + ((kk + 2) << 5));
      cA[1] = *(const bfrag*)(cp1 + ((kk + 2) << 5));
    }
    __builtin_amdgcn_s_setprio(1);
    #pragma unroll
    for (int mg = 0; mg < 4; ++mg) {
      int row = (mg << 4) + arow;
      int bo = (((kk + 1) << 6) + akB) ^ ((row & 7) << 4);
      bfrag a = *(const bfrag*)((const char*)(&bufA[row][0]) + bo);
      #pragma unroll
      for (int ng = 0; ng < 2; ++ng)
        acc2[mg][ng] = __builtin_amdgcn_mfma_f32_16x16x32_bf16(a, cB[ng], acc2[mg][ng], 0, 0, 0);
    }
    __builtin_amdgcn_s_setprio(0);
    if (kk + 3 < 16) {
      cB[0] = *(const bfrag*)(cp0 + ((kk + 3) << 5));
      cB[1] = *(const bfrag*)(cp1 + ((kk + 3) << 5));
    }
  }

  float bias2[2];
  #pragma unroll
  for (int ng = 0; ng < 2; ++ng) bias2[ng] = b2[(wave << 5) + (ng << 4) + arow];

  __syncthreads();   // all H1 reads done -> safe to overwrite with H2

  // epilogue 2: H2 overlays first 32KB of bufA
  ushort (*H2s)[H2D] = (ushort(*)[H2D])bufA;
  #pragma unroll
  for (int ng = 0; ng < 2; ++ng) {
    int col = (wave << 5) + (ng << 4) + arow;
    #pragma unroll
    for (int mg = 0; mg < 4; ++mg) {
      #pragma unroll
      for (int r = 0; r < 4; ++r) {
        int row = (mg << 4) + ((lane >> 4) << 2) + r;
        float v = fmaxf(acc2[mg][ng][r] + bias2[ng], 0.f);
        int bo = (col << 1) ^ ((row & 7) << 4);
        *(ushort*)((char*)(&H2s[row][0]) + bo) = f2b(v);
      }
    }
  }
  __syncthreads();   // H2 ready

  // ================= layer 3: out[m] = H2[m] . W3 + b3 (8 lanes per move) =================
  {
    const float b3v = b3[0];
    int row = tid >> 3;          // 0..63
    int oct = tid & 7;           // 32 k's each
    float sum = 0.f;
    #pragma unroll
    for (int j = 0; j < 4; ++j) {
      int kb = (oct << 6) + (j << 4);                 // byte offset of k*2
      int bo = kb ^ ((row & 7) << 4);
      bfrag hv = *(const bfrag*)((const char*)(&H2s[row][0]) + bo);
      int k0 = (oct << 5) + (j << 3);
      #pragma unroll
      for (int e = 0; e < 8; ++e)
        sum += b2f((ushort)hv[e]) * sW3[k0 + e];
    }
    sum += __shfl_xor(sum, 1);
    sum += __shfl_xor(sum, 2);
    sum += __shfl_xor(sum, 4);
    if (oct == 0) out[m0 + row] = sum + b3v;
  }
}

extern "C" void kernel_launch(void* const* d_in, const int* in_sizes, int n_in,
                              void* d_out, int out_size, void* d_ws, size_t ws_size,
                              hipStream_t stream) {
  const float* emb        = (const float*)d_in[0];
  const int*   edge_index = (const int*)d_in[1];
  const int*   move_idx   = (const int*)d_in[2];
  const float* W1         = (const float*)d_in[3];
  const float* b1         = (const float*)d_in[4];
  const float* W2         = (const float*)d_in[5];
  const float* b2         = (const float*)d_in[6];
  const float* W3         = (const float*)d_in[7];
  const float* b3         = (const float*)d_in[8];
  float* out = (float*)d_out;

  ushort* Wb   = (ushort*)d_ws;                 // W1b [512*512] + W2b [256*512]
  ushort* Embb = Wb + (H1D * KD + H2D * KD);    // bf16 emb table [100000*256]
  const size_t need = (size_t)(H1D * KD + H2D * KD + 100000 * DEMB) * 2;

  convert_w<<<384, 256, 0, stream>>>(W1, W2, Wb);

  if (ws_size >= need) {
    convert_emb<<<12500, 256, 0, stream>>>(emb, Embb);
    fused_mlp<1><<<N_MOVES / MT, NTHREADS, 0, stream>>>(
        emb, Embb, edge_index, move_idx,
        Wb, b1, Wb + H1D * KD, b2, W3, b3, out);
  } else {
    fused_mlp<0><<<N_MOVES / MT, NTHREADS, 0, stream>>>(
        emb, Embb, edge_index, move_idx,
        Wb, b1, Wb + H1D * KD, b2, W3, b3, out);
  }
}